// Round 3
// baseline (2658.368 us; speedup 1.0000x reference)
//
#include <hip/hip_runtime.h>
#include <stdint.h>

// Problem dims (fixed): T=256, B=128, I=512, H=1024, O=1
typedef __attribute__((ext_vector_type(8))) short short8;
typedef __attribute__((ext_vector_type(4))) float f32x4;
typedef __attribute__((ext_vector_type(4))) unsigned int u32x4;

__device__ __forceinline__ unsigned short f2bf(float f) {
  unsigned u = __float_as_uint(f);
  u += 0x7FFFu + ((u >> 16) & 1u);   // RNE
  return (unsigned short)(u >> 16);
}
__device__ __forceinline__ float bf2f(unsigned short s) {
  return __uint_as_float(((unsigned)s) << 16);
}
__device__ __forceinline__ float ftanh(float x) {
  float e = __expf(2.0f * x);
  return 1.0f - 2.0f / (e + 1.0f);
}

// ---------------- fp32 -> bf16 convert (vectorized, 8 elem/thread) ----------
__global__ __launch_bounds__(256) void cvt_kernel(const float* __restrict__ in,
                                                  unsigned short* __restrict__ out,
                                                  int n8) {
  int i = blockIdx.x * 256 + threadIdx.x;
  if (i >= n8) return;
  const float4* p = (const float4*)in + (size_t)i * 2;
  float4 a = p[0], b = p[1];
  uint4 o;
  o.x = (unsigned)f2bf(a.x) | ((unsigned)f2bf(a.y) << 16);
  o.y = (unsigned)f2bf(a.z) | ((unsigned)f2bf(a.w) << 16);
  o.z = (unsigned)f2bf(b.x) | ((unsigned)f2bf(b.y) << 16);
  o.w = (unsigned)f2bf(b.z) | ((unsigned)f2bf(b.w) << 16);
  ((uint4*)out)[i] = o;
}

// ---------------- xp GEMM: xp[m][n] = sum_k x[m][k]*W_ih[n][k] + b_ih[n]+b_hh[n]
__global__ __launch_bounds__(256) void gemm_xp(const unsigned short* __restrict__ A,
                                               const unsigned short* __restrict__ Bw,
                                               const float* __restrict__ b_ih,
                                               const float* __restrict__ b_hh,
                                               unsigned short* __restrict__ xp) {
  __shared__ unsigned short Al[8192];
  __shared__ unsigned short Bl[8192];
  int tid = threadIdx.x, lane = tid & 63, w = tid >> 6;
  int wm = w & 1, wn = w >> 1;
  int bx = blockIdx.x;
  int m0 = (bx >> 3) * 128, n0 = (bx & 7) * 128;

  f32x4 acc[4][4];
#pragma unroll
  for (int i = 0; i < 4; ++i)
#pragma unroll
    for (int jq = 0; jq < 4; ++jq) acc[i][jq] = (f32x4){0.f, 0.f, 0.f, 0.f};

  for (int kb = 0; kb < 512; kb += 64) {
#pragma unroll
    for (int i = 0; i < 4; ++i) {
      int S = (w * 4 + i) * 64 + lane;
      int row = S >> 3, pg = S & 7;
      int gk = ((pg ^ (row & 7)) << 3);
      const unsigned short* ga = A + (size_t)(m0 + row) * 512 + kb + gk;
      const unsigned short* gb = Bw + (size_t)(n0 + row) * 512 + kb + gk;
      __builtin_amdgcn_global_load_lds(
          (const __attribute__((address_space(1))) unsigned int*)ga,
          (__attribute__((address_space(3))) unsigned int*)&Al[(size_t)((w * 4 + i) * 64) * 8],
          16, 0, 0);
      __builtin_amdgcn_global_load_lds(
          (const __attribute__((address_space(1))) unsigned int*)gb,
          (__attribute__((address_space(3))) unsigned int*)&Bl[(size_t)((w * 4 + i) * 64) * 8],
          16, 0, 0);
    }
    asm volatile("s_waitcnt vmcnt(0)" ::: "memory");
    __syncthreads();

#pragma unroll
    for (int c = 0; c < 2; ++c) {
      short8 av[4], bv[4];
      int gg = c * 4 + (lane >> 4);
#pragma unroll
      for (int mt = 0; mt < 4; ++mt) {
        int rowa = wm * 64 + mt * 16 + (lane & 15);
        av[mt] = *(const short8*)&Al[(rowa * 8 + (gg ^ (rowa & 7))) * 8];
        int rowb = wn * 64 + mt * 16 + (lane & 15);
        bv[mt] = *(const short8*)&Bl[(rowb * 8 + (gg ^ (rowb & 7))) * 8];
      }
#pragma unroll
      for (int mt = 0; mt < 4; ++mt)
#pragma unroll
        for (int nt = 0; nt < 4; ++nt)
          acc[mt][nt] = __builtin_amdgcn_mfma_f32_16x16x32_bf16(av[mt], bv[nt], acc[mt][nt], 0, 0, 0);
    }
    __syncthreads();
  }

  int cl = lane & 15, qd = lane >> 4;
#pragma unroll
  for (int nt = 0; nt < 4; ++nt) {
    int col = n0 + wn * 64 + nt * 16 + cl;
    float bias = b_ih[col] + b_hh[col];
#pragma unroll
    for (int mt = 0; mt < 4; ++mt) {
#pragma unroll
      for (int r = 0; r < 4; ++r) {
        int m = m0 + wm * 64 + mt * 16 + qd * 4 + r;
        xp[(size_t)m * 1024 + col] = f2bf(acc[mt][nt][r] + bias);
      }
    }
  }
}

// ---------------- the scan + fused head ------------------------------------
// 64 WGs x 256 threads: group g = blk&7 (16 batches), slice j = blk>>3 covers
// H cols [j*128, j*128+128) as 4 waves x 2 MFMA tiles. W_hh lives in REGISTERS
// (256 VGPR B-frags/wave; 1 WG/CU so 512-VGPR budget). Sync: h words published
// as self-validating (tag<<16)|bf16 dwords, sc0 sc1 fire-and-forget; consumers
// poll the data directly (one MALL round trip on the critical path), strip tags
// into an LDS A-buffer, MFMA. Double-buffered slots are race-free by
// backpressure (publishing h[s+1] requires having read all of h[s]).
// Head (O=1) fused: fp32 partials shfl-reduced + atomicAdd per (t,b).
#define ASTRIDE 520  // shorts per k-chunk row (64*8 + 8 pad: 4-way max bank conflict)
__global__ __launch_bounds__(256, 1) void scan_kernel(
    const float* __restrict__ Whh, const unsigned short* __restrict__ xp,
    const float* __restrict__ Wfc, const float* __restrict__ bfc,
    unsigned* __restrict__ sync, float* __restrict__ out) {
  __shared__ unsigned short Abuf[32 * ASTRIDE];  // 33280 B
  const int tid = threadIdx.x;
  const int lane = tid & 63, w = tid >> 6;
  const int g = blockIdx.x & 7, j = blockIdx.x >> 3;
  const int r = lane & 15, q = lane >> 4;
  const int b0 = g * 16;
  const float bfcv = bfc[0];

  // ---- W_hh -> register B-frags: lane (r,q) of wave w, tile tl holds
  // W[j*128 + tl*64 + w*16 + r][c*32 + q*8 + 0..7], fp32->bf16.
  short8 Bfrag[2][32];
#pragma unroll
  for (int tl = 0; tl < 2; ++tl) {
    const float* wsrc = Whh + (size_t)(j * 128 + tl * 64 + w * 16 + r) * 1024 + q * 8;
#pragma unroll
    for (int c = 0; c < 32; ++c) {
      float4 v0 = *(const float4*)(wsrc + c * 32);
      float4 v1 = *(const float4*)(wsrc + c * 32 + 4);
      short8 sv;
      sv[0] = (short)f2bf(v0.x); sv[1] = (short)f2bf(v0.y);
      sv[2] = (short)f2bf(v0.z); sv[3] = (short)f2bf(v0.w);
      sv[4] = (short)f2bf(v1.x); sv[5] = (short)f2bf(v1.y);
      sv[6] = (short)f2bf(v1.z); sv[7] = (short)f2bf(v1.w);
      Bfrag[tl][c] = sv;
    }
  }

  int xcol[2];
  float wfcv[2];
#pragma unroll
  for (int tl = 0; tl < 2; ++tl) {
    xcol[tl] = j * 128 + tl * 64 + w * 16 + r;
    wfcv[tl] = Wfc[xcol[tl]];
  }

  // ---- step 0: every WG computes FULL h0 = tanh(xp[0]) locally (no sync).
  // Thread t covers batch r0=t/16, cols col0..col0+64.
  {
    const int r0 = tid >> 4, col0 = (tid & 15) * 64;
    const unsigned short* xsrc = xp + (size_t)(b0 + r0) * 1024 + col0;
    float hv[64];
#pragma unroll
    for (int i = 0; i < 64; ++i) hv[i] = ftanh(bf2f(xsrc[i]));
#pragma unroll
    for (int cc = 0; cc < 2; ++cc) {
      int c = (tid & 15) * 2 + cc;
#pragma unroll
      for (int qq = 0; qq < 4; ++qq) {
        short8 sv;
#pragma unroll
        for (int jj = 0; jj < 8; ++jj) sv[jj] = (short)f2bf(hv[cc * 32 + qq * 8 + jj]);
        *(short8*)&Abuf[(size_t)c * ASTRIDE + (qq * 16 + r0) * 8] = sv;
      }
    }
    // head contribution for t=0: own 64-col run only (slice owner check)
    if (((tid & 15) >> 1) == j) {
      float p = 0.f;
#pragma unroll
      for (int i = 0; i < 64; ++i) p += hv[i] * Wfc[col0 + i];
      if (j == 0 && (tid & 15) == 0) p += bfcv;
      atomicAdd(out + b0 + r0, p);
    }
  }
  __syncthreads();

  unsigned* syncg = sync + (size_t)g * 2 * 16384;  // [slot 2][16][1024] u32
  int guard = 0;

  for (int s = 1; s < 256; ++s) {
    // xp prefetch (plain cached loads, in flight during the poll)
    float xpv[2][4];
#pragma unroll
    for (int tl = 0; tl < 2; ++tl)
#pragma unroll
      for (int rr = 0; rr < 4; ++rr)
        xpv[tl][rr] = bf2f(xp[((size_t)s * 128 + b0 + q * 4 + rr) * 1024 + xcol[tl]]);

    if (s >= 2) {
      // ---- poll tagged h[s-1]: thread t polls its 64 words (256 B).
      const unsigned exp_tag = (unsigned)(s - 1);
      const unsigned* base = syncg + ((s - 1) & 1) * 16384 + (size_t)tid * 64;
      u32x4 st[16];
      unsigned ok = 0;
      while (ok != 0xFFFFu) {
#pragma unroll
        for (int i = 0; i < 16; ++i) {
          if (!(ok & (1u << i))) {
            asm volatile("global_load_dwordx4 %0, %1, off sc0 sc1"
                         : "=v"(st[i])
                         : "v"((unsigned long long)(uintptr_t)(base + i * 4))
                         : "memory");
          }
        }
        asm volatile("s_waitcnt vmcnt(0)" ::: "memory");
#pragma unroll
        for (int i = 0; i < 16; ++i) {
          if (!(ok & (1u << i))) {
            bool good = (st[i].x >> 16) == exp_tag && (st[i].y >> 16) == exp_tag &&
                        (st[i].z >> 16) == exp_tag && (st[i].w >> 16) == exp_tag;
            ok |= good ? (1u << i) : 0u;
          }
        }
        if (++guard > (1 << 16)) break;  // fail-safe: terminate (will fail check)
      }
      __syncthreads();  // prior step's Abuf reads complete before overwrite
      // ---- strip tags -> Abuf (A-frag layout)
      const int r0 = tid >> 4;
#pragma unroll
      for (int cc = 0; cc < 2; ++cc) {
        int c = (tid & 15) * 2 + cc;
#pragma unroll
        for (int qq = 0; qq < 4; ++qq) {
          u32x4 a = st[cc * 8 + qq * 2], b = st[cc * 8 + qq * 2 + 1];
          short8 sv;
          sv[0] = (short)a.x; sv[1] = (short)a.y; sv[2] = (short)a.z; sv[3] = (short)a.w;
          sv[4] = (short)b.x; sv[5] = (short)b.y; sv[6] = (short)b.z; sv[7] = (short)b.w;
          *(short8*)&Abuf[(size_t)c * ASTRIDE + (qq * 16 + r0) * 8] = sv;
        }
      }
      __syncthreads();
    }

    // ---- MFMA: two independent 16x16 tiles per wave over K=1024
    f32x4 acc0 = (f32x4){0.f, 0.f, 0.f, 0.f};
    f32x4 acc1 = (f32x4){0.f, 0.f, 0.f, 0.f};
#pragma unroll
    for (int c = 0; c < 32; ++c) {
      short8 av = *(const short8*)&Abuf[(size_t)c * ASTRIDE + lane * 8];
      acc0 = __builtin_amdgcn_mfma_f32_16x16x32_bf16(av, Bfrag[0][c], acc0, 0, 0, 0);
      acc1 = __builtin_amdgcn_mfma_f32_16x16x32_bf16(av, Bfrag[1][c], acc1, 0, 0, 0);
    }

    // ---- epilogue: tanh, fused head, publish tagged h[s]
    unsigned* pubbase = syncg + (s & 1) * 16384;
#pragma unroll
    for (int tl = 0; tl < 2; ++tl) {
      f32x4 acc = tl ? acc1 : acc0;
#pragma unroll
      for (int rr = 0; rr < 4; ++rr) {
        float h = ftanh(acc[rr] + xpv[tl][rr]);
        float p = h * wfcv[tl];
        p += __shfl_xor(p, 1, 64);
        p += __shfl_xor(p, 2, 64);
        p += __shfl_xor(p, 4, 64);
        p += __shfl_xor(p, 8, 64);
        if (r == 0) {
          if (j == 0 && w == 0 && tl == 0) p += bfcv;
          atomicAdd(out + (size_t)s * 128 + b0 + q * 4 + rr, p);
        }
        unsigned word = ((unsigned)s << 16) | (unsigned)f2bf(h);
        unsigned* pa = pubbase + (size_t)(q * 4 + rr) * 1024 + xcol[tl];
        asm volatile("global_store_dword %0, %1, off sc0 sc1"
                     :: "v"((unsigned long long)(uintptr_t)pa), "v"(word) : "memory");
      }
    }
  }
}

// ---------------- launcher --------------------------------------------------
extern "C" void kernel_launch(void* const* d_in, const int* in_sizes, int n_in,
                              void* d_out, int out_size, void* d_ws, size_t ws_size,
                              hipStream_t stream) {
  (void)in_sizes; (void)n_in; (void)out_size; (void)ws_size;
  const float* x   = (const float*)d_in[0];
  const float* Wih = (const float*)d_in[1];
  const float* Whh = (const float*)d_in[2];
  const float* bih = (const float*)d_in[3];
  const float* bhh = (const float*)d_in[4];
  const float* Wfc = (const float*)d_in[5];
  const float* bfc = (const float*)d_in[6];
  float* out = (float*)d_out;

  char* ws = (char*)d_ws;
  // Layout: xp 64 MB | xb 32 MB | wb 1 MB | sync 1 MB  (total 98 MB)
  unsigned short* xp = (unsigned short*)(ws);
  unsigned short* xb = (unsigned short*)(ws + 67108864);
  unsigned short* wb = (unsigned short*)(ws + 67108864 + 33554432);
  unsigned* sync     = (unsigned*)(ws + 67108864 + 33554432 + 1048576);

  // d_out is 0xAA-poisoned; head accumulates via atomics -> zero it.
  hipMemsetAsync(out, 0, (size_t)out_size * 4, stream);
  // sync buffer needs NO init: poison tag 0xAAAA never matches tags 1..255.

  cvt_kernel<<<8192, 256, 0, stream>>>(x, xb, 2097152);     // x fp32 -> bf16
  cvt_kernel<<<256, 256, 0, stream>>>(Wih, wb, 65536);      // W_ih fp32 -> bf16
  gemm_xp<<<2048, 256, 0, stream>>>(xb, wb, bih, bhh, xp);  // xp = x@W_ih^T + b
  scan_kernel<<<64, 256, 0, stream>>>(Whh, xp, Wfc, bfc, sync, out);
}

// Round 4
// 1590.072 us; speedup vs baseline: 1.6719x; 1.6719x over previous
//
#include <hip/hip_runtime.h>
#include <stdint.h>

// Problem dims (fixed): T=256, B=128, I=512, H=1024, O=1
typedef __attribute__((ext_vector_type(8))) short short8;
typedef __attribute__((ext_vector_type(4))) float f32x4;
typedef __attribute__((ext_vector_type(4))) unsigned int u32x4;

__device__ __forceinline__ unsigned short f2bf(float f) {
  unsigned u = __float_as_uint(f);
  u += 0x7FFFu + ((u >> 16) & 1u);   // RNE
  return (unsigned short)(u >> 16);
}
__device__ __forceinline__ float bf2f(unsigned short s) {
  return __uint_as_float(((unsigned)s) << 16);
}
__device__ __forceinline__ float ftanh(float x) {
  float e = __expf(2.0f * x);
  return 1.0f - 2.0f / (e + 1.0f);
}

// ---------------- fp32 -> bf16 convert (vectorized, 8 elem/thread) ----------
__global__ __launch_bounds__(256) void cvt_kernel(const float* __restrict__ in,
                                                  unsigned short* __restrict__ out,
                                                  int n8) {
  int i = blockIdx.x * 256 + threadIdx.x;
  if (i >= n8) return;
  const float4* p = (const float4*)in + (size_t)i * 2;
  float4 a = p[0], b = p[1];
  uint4 o;
  o.x = (unsigned)f2bf(a.x) | ((unsigned)f2bf(a.y) << 16);
  o.y = (unsigned)f2bf(a.z) | ((unsigned)f2bf(a.w) << 16);
  o.z = (unsigned)f2bf(b.x) | ((unsigned)f2bf(b.y) << 16);
  o.w = (unsigned)f2bf(b.z) | ((unsigned)f2bf(b.w) << 16);
  ((uint4*)out)[i] = o;
}

// ---------------- xp GEMM: xp[m][n] = sum_k x[m][k]*W_ih[n][k] + b_ih[n]+b_hh[n]
__global__ __launch_bounds__(256) void gemm_xp(const unsigned short* __restrict__ A,
                                               const unsigned short* __restrict__ Bw,
                                               const float* __restrict__ b_ih,
                                               const float* __restrict__ b_hh,
                                               unsigned short* __restrict__ xp) {
  __shared__ unsigned short Al[8192];
  __shared__ unsigned short Bl[8192];
  int tid = threadIdx.x, lane = tid & 63, w = tid >> 6;
  int wm = w & 1, wn = w >> 1;
  int bx = blockIdx.x;
  int m0 = (bx >> 3) * 128, n0 = (bx & 7) * 128;

  f32x4 acc[4][4];
#pragma unroll
  for (int i = 0; i < 4; ++i)
#pragma unroll
    for (int jq = 0; jq < 4; ++jq) acc[i][jq] = (f32x4){0.f, 0.f, 0.f, 0.f};

  for (int kb = 0; kb < 512; kb += 64) {
#pragma unroll
    for (int i = 0; i < 4; ++i) {
      int S = (w * 4 + i) * 64 + lane;
      int row = S >> 3, pg = S & 7;
      int gk = ((pg ^ (row & 7)) << 3);
      const unsigned short* ga = A + (size_t)(m0 + row) * 512 + kb + gk;
      const unsigned short* gb = Bw + (size_t)(n0 + row) * 512 + kb + gk;
      __builtin_amdgcn_global_load_lds(
          (const __attribute__((address_space(1))) unsigned int*)ga,
          (__attribute__((address_space(3))) unsigned int*)&Al[(size_t)((w * 4 + i) * 64) * 8],
          16, 0, 0);
      __builtin_amdgcn_global_load_lds(
          (const __attribute__((address_space(1))) unsigned int*)gb,
          (__attribute__((address_space(3))) unsigned int*)&Bl[(size_t)((w * 4 + i) * 64) * 8],
          16, 0, 0);
    }
    asm volatile("s_waitcnt vmcnt(0)" ::: "memory");
    __syncthreads();

#pragma unroll
    for (int c = 0; c < 2; ++c) {
      short8 av[4], bv[4];
      int gg = c * 4 + (lane >> 4);
#pragma unroll
      for (int mt = 0; mt < 4; ++mt) {
        int rowa = wm * 64 + mt * 16 + (lane & 15);
        av[mt] = *(const short8*)&Al[(rowa * 8 + (gg ^ (rowa & 7))) * 8];
        int rowb = wn * 64 + mt * 16 + (lane & 15);
        bv[mt] = *(const short8*)&Bl[(rowb * 8 + (gg ^ (rowb & 7))) * 8];
      }
#pragma unroll
      for (int mt = 0; mt < 4; ++mt)
#pragma unroll
        for (int nt = 0; nt < 4; ++nt)
          acc[mt][nt] = __builtin_amdgcn_mfma_f32_16x16x32_bf16(av[mt], bv[nt], acc[mt][nt], 0, 0, 0);
    }
    __syncthreads();
  }

  int cl = lane & 15, qd = lane >> 4;
#pragma unroll
  for (int nt = 0; nt < 4; ++nt) {
    int col = n0 + wn * 64 + nt * 16 + cl;
    float bias = b_ih[col] + b_hh[col];
#pragma unroll
    for (int mt = 0; mt < 4; ++mt) {
#pragma unroll
      for (int r = 0; r < 4; ++r) {
        int m = m0 + wm * 64 + mt * 16 + qd * 4 + r;
        xp[(size_t)m * 1024 + col] = f2bf(acc[mt][nt][r] + bias);
      }
    }
  }
}

// ---------------- the scan + fused head ------------------------------------
// 64 WGs x 512 threads (8 waves): group g = blk>>3 (16 batches), producer
// p = blk&7 owns cols [p*128, p*128+128); wave w owns the 16x16 tile at
// cols p*128+w*16. W_hh B-frags: 128 VGPRs/wave (~210 total, no spill).
// Per step: publish h[s] slice (sc0 sc1 write-through, fresh addresses per
// step) -> vmcnt(0) ack -> tag 's' into 8 per-consumer slots. Consumer wave 0
// polls its own 8 tag words (32 B, no shared hot line), then all threads
// plain-load the group's 16x1024 h[s-1] (lines never cached pre-publish ->
// cannot be stale; r2-validated pattern) into a conflict-free piece-ordered
// LDS A-buffer. Head (O=1) fused via shfl-reduce + atomicAdd off the
// critical path. h0 computed locally by every WG (no sync for step 1).
__global__ __launch_bounds__(512, 2) void scan_kernel(
    const float* __restrict__ Whh, const unsigned short* __restrict__ xp,
    const float* __restrict__ Wfc, const float* __restrict__ bfc,
    unsigned short* __restrict__ hs, int* __restrict__ tags,
    float* __restrict__ out) {
  __shared__ __align__(16) unsigned short Abuf[2048 * 8];     // 32 KB, piece m @ Abuf[m*8]
  __shared__ __align__(16) unsigned short ptile[8][16 * 32];  // 8 KB pack tiles
  const int tid = threadIdx.x;
  const int lane = tid & 63, w = tid >> 6;
  const int g = blockIdx.x >> 3, p = blockIdx.x & 7;
  const int r = lane & 15, q = lane >> 4;
  const int b0 = g * 16;
  const int gcol = p * 128 + w * 16 + r;   // this lane's output column
  const float bfcv = bfc[0];
  const float wfcv = Wfc[gcol];

  // ---- W_hh -> register B-frags: lane (r,q) holds W[gcol][c*32+q*8 ..+7]
  short8 Bfrag[32];
  {
    const float* wsrc = Whh + (size_t)gcol * 1024 + q * 8;
#pragma unroll
    for (int c = 0; c < 32; ++c) {
      float4 v0 = *(const float4*)(wsrc + c * 32);
      float4 v1 = *(const float4*)(wsrc + c * 32 + 4);
      short8 sv;
      sv[0] = (short)f2bf(v0.x); sv[1] = (short)f2bf(v0.y);
      sv[2] = (short)f2bf(v0.z); sv[3] = (short)f2bf(v0.w);
      sv[4] = (short)f2bf(v1.x); sv[5] = (short)f2bf(v1.y);
      sv[6] = (short)f2bf(v1.z); sv[7] = (short)f2bf(v1.w);
      Bfrag[c] = sv;
    }
  }

  // ---- step 0: full h0 = tanh(xp[0]) for this group, locally, into Abuf.
  // Piece m (c=m>>6, l=m&63): batch l&15, cols c*32 + (l>>4)*8 ..+7.
  {
#pragma unroll
    for (int i = 0; i < 4; ++i) {
      int m = tid + i * 512;
      int l = m & 63, c = m >> 6;
      int bb = l & 15, q2 = l >> 4;
      const unsigned short* src = xp + (size_t)(b0 + bb) * 1024 + c * 32 + q2 * 8;
      u32x4 xv = *(const u32x4*)src;
      const unsigned short* xs = (const unsigned short*)&xv;
      short8 sv;
      float pp = 0.f;
#pragma unroll
      for (int jj = 0; jj < 8; ++jj) {
        float h = ftanh(bf2f(xs[jj]));
        sv[jj] = (short)f2bf(h);
        pp += h * Wfc[c * 32 + q2 * 8 + jj];
      }
      *(short8*)&Abuf[(size_t)m * 8] = sv;
      if (p == 0) {               // head t=0: one WG per group contributes
        if (m < 16) pp += bfcv;   // c==0,q2==0: once per batch
        atomicAdd(out + b0 + bb, pp);
      }
    }
  }
  __syncthreads();

  const int* mytags = tags + (size_t)(g * 8 + p) * 16;
  for (int s = 1; s < 256; ++s) {
    if (s >= 2) {
      // ---- wave 0 polls its own 8 tag words (>= s-1); others park at B1.
      if (w == 0) {
        const int* ta = mytags + lane;
        int guard = 0;
        while (true) {
          int tv = 0x7fffffff;
          if (lane < 8) {
            asm volatile("global_load_dword %0, %1, off sc0 sc1\n\ts_waitcnt vmcnt(0)"
                         : "=v"(tv)
                         : "v"((unsigned long long)(uintptr_t)ta)
                         : "memory");
          }
          if (__all(tv >= s - 1)) break;
          if (++guard > (1 << 18)) break;  // fail-safe: terminate (fails check)
        }
      }
      __syncthreads();  // B1: tags passed; prev step's Abuf reads done

      // ---- strip h[s-1] -> Abuf (plain cached loads; conflict-free writes)
      const unsigned short* hbase = hs + (size_t)(s - 1) * 131072;
#pragma unroll
      for (int i = 0; i < 4; ++i) {
        int m = tid + i * 512;
        int l = m & 63, c = m >> 6;
        int bb = l & 15, q2 = l >> 4;
        u32x4 v = *(const u32x4*)(hbase + (size_t)(b0 + bb) * 1024 + c * 32 + q2 * 8);
        *(u32x4*)&Abuf[(size_t)m * 8] = v;
      }
      __syncthreads();  // B2: Abuf ready
    }

    // ---- xp for this step (issued early; consumed ~after MFMA)
    float xpv[4];
#pragma unroll
    for (int rr = 0; rr < 4; ++rr)
      xpv[rr] = bf2f(xp[((size_t)s * 128 + b0 + q * 4 + rr) * 1024 + gcol]);

    // ---- MFMA: 16x16 tile over K=1024, two independent chains
    f32x4 acc0 = (f32x4){0.f, 0.f, 0.f, 0.f};
    f32x4 acc1 = (f32x4){0.f, 0.f, 0.f, 0.f};
#pragma unroll
    for (int c = 0; c < 16; ++c) {
      short8 a0 = *(const short8*)&Abuf[(size_t)(2 * c) * 512 + lane * 8];
      short8 a1 = *(const short8*)&Abuf[(size_t)(2 * c + 1) * 512 + lane * 8];
      acc0 = __builtin_amdgcn_mfma_f32_16x16x32_bf16(a0, Bfrag[2 * c], acc0, 0, 0, 0);
      acc1 = __builtin_amdgcn_mfma_f32_16x16x32_bf16(a1, Bfrag[2 * c + 1], acc1, 0, 0, 0);
    }

    // ---- h = tanh(acc + xp); pack wave tile [batch 16][col 16] (stride 32)
    float hv4[4];
#pragma unroll
    for (int rr = 0; rr < 4; ++rr) {
      hv4[rr] = ftanh(acc0[rr] + acc1[rr] + xpv[rr]);
      ptile[w][(q * 4 + rr) * 32 + r] = f2bf(hv4[rr]);
    }
    __syncthreads();  // B3: ptile visible (cross-lane via LDS)

    // ---- publish h[s] slice: 32 lanes store 16 rows x 2 dwordx4 (sc0 sc1)
    if (lane < 32) {
      int row = lane & 15, half = lane >> 4;
      u32x4 v = *(const u32x4*)&ptile[w][row * 32 + half * 8];
      unsigned long long addr = (unsigned long long)(uintptr_t)(
          hs + ((size_t)s * 128 + b0 + row) * 1024 + p * 128 + w * 16 + half * 8);
      asm volatile("global_store_dwordx4 %0, %1, off sc0 sc1"
                   :: "v"(addr), "v"(v) : "memory");
    }
    asm volatile("s_waitcnt vmcnt(0)" ::: "memory");  // data at MALL
    __syncthreads();  // B4: all waves' stores acked
    if (w == 0 && lane < 8) {
      int* ta = tags + (size_t)(g * 8 + lane) * 16 + p;  // per-consumer slot
      asm volatile("global_store_dword %0, %1, off sc0 sc1"
                   :: "v"((unsigned long long)(uintptr_t)ta), "v"(s) : "memory");
    }

    // ---- fused head (off critical path)
#pragma unroll
    for (int rr = 0; rr < 4; ++rr) {
      float pp = hv4[rr] * wfcv;
      pp += __shfl_xor(pp, 1, 64);
      pp += __shfl_xor(pp, 2, 64);
      pp += __shfl_xor(pp, 4, 64);
      pp += __shfl_xor(pp, 8, 64);
      if (r == 0) {
        if (p == 0 && w == 0) pp += bfcv;
        atomicAdd(out + (size_t)s * 128 + b0 + q * 4 + rr, pp);
      }
    }
  }
}

// ---------------- launcher --------------------------------------------------
extern "C" void kernel_launch(void* const* d_in, const int* in_sizes, int n_in,
                              void* d_out, int out_size, void* d_ws, size_t ws_size,
                              hipStream_t stream) {
  (void)in_sizes; (void)n_in; (void)ws_size;
  const float* x   = (const float*)d_in[0];
  const float* Wih = (const float*)d_in[1];
  const float* Whh = (const float*)d_in[2];
  const float* bih = (const float*)d_in[3];
  const float* bhh = (const float*)d_in[4];
  const float* Wfc = (const float*)d_in[5];
  const float* bfc = (const float*)d_in[6];
  float* out = (float*)d_out;

  char* ws = (char*)d_ws;
  // Layout: xp 64 MB @0 | hs 64 MB @64MB | xb 32 MB aliases hs (dead before
  // scan) | wb 1 MB @96MB | tags 4 KB @128MB. (r2-proven footprint.)
  unsigned short* xp = (unsigned short*)(ws);
  unsigned short* hs = (unsigned short*)(ws + 67108864);
  unsigned short* xb = (unsigned short*)(ws + 67108864);
  unsigned short* wb = (unsigned short*)(ws + 67108864 + 33554432);
  int* tags          = (int*)(ws + 134217728);

  // d_out is 0xAA-poisoned; head accumulates via atomics -> zero it.
  // tags need NO init: poison is negative under signed compare.
  hipMemsetAsync(out, 0, (size_t)out_size * 4, stream);

  cvt_kernel<<<8192, 256, 0, stream>>>(x, xb, 2097152);     // x fp32 -> bf16
  cvt_kernel<<<256, 256, 0, stream>>>(Wih, wb, 65536);      // W_ih fp32 -> bf16
  gemm_xp<<<2048, 256, 0, stream>>>(xb, wb, bih, bhh, xp);  // xp = x@W_ih^T + b
  scan_kernel<<<64, 512, 0, stream>>>(Whh, xp, Wfc, bfc, hs, tags, out);
}